// Round 4
// baseline (462.329 us; speedup 1.0000x reference)
//
#include <hip/hip_runtime.h>
#include <hip/hip_bf16.h>
#include <math.h>

#define N_  8
#define C_  528
#define T_  16
#define H_  32
#define W_  32
#define HW_ 1024
#define R_  1024
#define OUT_ 8
#define SR_ 2
#define SCALE_ (1.0f/16.0f)

// ---------------------------------------------------------------------------
// Kernel 1: feat_t[n][p][c] = mean_t x[n][c][t][p], NCHW -> N(HW)C transpose.
// (round-3 version: measured at the HBM floor, keep.)
// ---------------------------------------------------------------------------
__global__ __launch_bounds__(256) void mean_transpose(
    const float* __restrict__ x, float* __restrict__ feat_t) {
  const int p0 = blockIdx.x * 256;   // 4 quarters of HW
  const int c0 = blockIdx.y * 16;    // 33 groups * 16 = 528 exact
  const int n  = blockIdx.z;

  __shared__ float tile[4][64][17];  // 17.4 KB

  const int tid  = threadIdx.x;
  const int lane = tid & 63;
  const int w    = tid >> 6;         // wave id 0..3
  const float inv_t = 1.0f / 16.0f;

  #pragma unroll
  for (int k = 0; k < 4; ++k) {
    const int c_local = w * 4 + k;
    const int c = c0 + c_local;
    const float* src = x + ((size_t)(n * C_ + c) * T_) * HW_ + p0 + lane * 4;
    float4 acc = make_float4(0.f, 0.f, 0.f, 0.f);
    #pragma unroll
    for (int t = 0; t < T_; ++t) {
      const float4 v = *(const float4*)(src + t * HW_);  // wave: 1KB contig
      acc.x += v.x; acc.y += v.y; acc.z += v.z; acc.w += v.w;
    }
    tile[0][lane][c_local] = acc.x * inv_t;  // p = 4*lane+0
    tile[1][lane][c_local] = acc.y * inv_t;
    tile[2][lane][c_local] = acc.z * inv_t;
    tile[3][lane][c_local] = acc.w * inv_t;
  }
  __syncthreads();

  // write phase: 256 p-rows x 16 c = 1024 float4, 4 per thread.
  const int c4 = (tid & 3) * 4;
  #pragma unroll
  for (int k = 0; k < 4; ++k) {
    const int p_out = (tid >> 2) + 64 * k;
    const int i = p_out & 3;
    const int l = p_out >> 2;
    float4 v;
    v.x = tile[i][l][c4 + 0];
    v.y = tile[i][l][c4 + 1];
    v.z = tile[i][l][c4 + 2];
    v.w = tile[i][l][c4 + 3];
    *(float4*)&feat_t[((size_t)n * HW_ + p0 + p_out) * C_ + c0 + c4] = v;
  }
}

// ---------------------------------------------------------------------------
// Kernel 2: ONE WAVE PER ROI. 1024 blocks x 64 threads.
// Workgroup == wavefront -> every __syncthreads() is barrier-elided (waitcnt
// only). Gather accumulates in registers (3x float4 covering 132 c-quads);
// no pooledP round-trip, no Y-reduce phase, no narrow sub-wave phases.
// ---------------------------------------------------------------------------
__global__ __launch_bounds__(64) void roi_mlp(
    const float* __restrict__ feat_t, const float* __restrict__ bbox,
    const float* __restrict__ W1, const float* __restrict__ b1,
    const float* __restrict__ W2, const float* __restrict__ b2,
    const float* __restrict__ W3, const float* __restrict__ b3,
    float* __restrict__ out) {
  const int r = blockIdx.x;
  const int lane = threadIdx.x;

  __shared__ float sAy[32], sAx[32];
  __shared__ __align__(16) float pooled[C_];
  __shared__ __align__(8)  float h1[128];
  __shared__ int sbounds[5];  // ylo,yhi,xlo,xhi,bidx

  if (lane < 32) { sAy[lane] = 0.f; sAx[lane] = 0.f; }
  __syncthreads();   // single-wave: waitcnt only

  // --- Phase A: per-axis separable weights + support bounds (lanes 0-31) --
  if (lane < 32) {
    const bool is_y = (lane < 16);
    const int  i    = lane & 15;
    const float s1  = bbox[r * 5 + (is_y ? 2 : 1)] * SCALE_ - 0.5f;
    const float s2  = bbox[r * 5 + (is_y ? 4 : 3)] * SCALE_ - 0.5f;
    const float bin = (s2 - s1) * (1.0f / OUT_);
    const float v   = s1 + ((float)i + 0.5f) * (bin * 0.5f);
    const bool valid = (v >= -1.0f) && (v <= (float)H_);
    int lo = 999, hi = -1;
    if (valid) {
      float vc = fminf(fmaxf(v, 0.0f), (float)(H_ - 1));
      float lo_f = floorf(vc);
      float fr = vc - lo_f;
      lo = (int)lo_f;
      hi = min(lo + 1, H_ - 1);
      float* A = is_y ? sAy : sAx;
      atomicAdd(&A[lo], 1.0f - fr);
      atomicAdd(&A[hi], fr);
    }
    int mn = lo, mx = hi;
    #pragma unroll
    for (int m = 8; m >= 1; m >>= 1) {
      mn = min(mn, __shfl_xor(mn, m, 16));
      mx = max(mx, __shfl_xor(mx, m, 16));
    }
    if (lane == 0)  { sbounds[0] = mn; sbounds[1] = mx;
                      sbounds[4] = (int)bbox[r * 5]; }
    if (lane == 16) { sbounds[2] = mn; sbounds[3] = mx; }
  }
  __syncthreads();

  const int ylo = sbounds[0], yhi = sbounds[1];
  const int xlo = sbounds[2], xhi = sbounds[3];
  const int bidx = sbounds[4];
  const int ny = yhi - ylo + 1;
  const int nx = xhi - xlo + 1;

  // --- Gather into registers: lane owns c-quads {lane, 64+lane, 128+lane<4}
  float4 a0 = make_float4(0.f, 0.f, 0.f, 0.f);
  float4 a1 = a0, a2 = a0;
  if (ny > 0 && nx > 0) {
    const float* fb = feat_t + (size_t)bidx * HW_ * C_;
    for (int yk = 0; yk < ny; ++yk) {
      const float wy = sAy[ylo + yk];
      const float4* row =
          (const float4*)(fb + (size_t)((ylo + yk) * W_ + xlo) * C_);
      for (int xk = 0; xk < nx; ++xk) {
        const float wq = wy * sAx[xlo + xk];
        const float4* p = row + xk * 132;
        const float4 v0 = p[lane];
        a0.x += wq * v0.x; a0.y += wq * v0.y;
        a0.z += wq * v0.z; a0.w += wq * v0.w;
        const float4 v1 = p[64 + lane];
        a1.x += wq * v1.x; a1.y += wq * v1.y;
        a1.z += wq * v1.z; a1.w += wq * v1.w;
        if (lane < 4) {
          const float4 v2 = p[128 + lane];
          a2.x += wq * v2.x; a2.y += wq * v2.y;
          a2.z += wq * v2.z; a2.w += wq * v2.w;
        }
      }
    }
  }
  {
    const float inv = 1.0f / 256.0f;
    a0.x *= inv; a0.y *= inv; a0.z *= inv; a0.w *= inv;
    a1.x *= inv; a1.y *= inv; a1.z *= inv; a1.w *= inv;
    ((float4*)pooled)[lane]      = a0;
    ((float4*)pooled)[64 + lane] = a1;
    if (lane < 4) {
      a2.x *= inv; a2.y *= inv; a2.z *= inv; a2.w *= inv;
      ((float4*)pooled)[128 + lane] = a2;
    }
  }
  __syncthreads();

  // --- Layer 1 (528 -> 128, relu): lane computes j = 2*lane, 2*lane+1 -----
  {
    const int j2 = lane * 2;
    float acc0 = 0.f, acc1 = 0.f;
    const float* w = W1 + j2;
    #pragma unroll 4
    for (int c = 0; c < C_; ++c) {
      const float2 wv = *(const float2*)(w + (size_t)c * 128);
      const float pv = pooled[c];      // LDS broadcast
      acc0 += pv * wv.x;
      acc1 += pv * wv.y;
    }
    float2 hv;
    hv.x = fmaxf(acc0 + b1[j2],     0.f);
    hv.y = fmaxf(acc1 + b1[j2 + 1], 0.f);
    *(float2*)&h1[j2] = hv;
  }
  __syncthreads();

  // --- Layers 2+3 fused, register-only after h1 ---------------------------
  {
    const int j  = lane & 31;
    const int kh = lane >> 5;            // K-half 0/1
    float acc = 0.f;
    #pragma unroll 8
    for (int i = 0; i < 64; ++i) {
      const int k = kh * 64 + i;
      acc += h1[k] * W2[k * 32 + j];
    }
    acc += __shfl_xor(acc, 32);          // combine K-halves; both halves full
    float t = (acc + b2[j]) * W3[j];
    #pragma unroll
    for (int off = 16; off >= 1; off >>= 1) t += __shfl_xor(t, off, 32);
    if (lane == 0) out[r] = 1.0f / (1.0f + expf(-(t + b3[0])));
  }
}

extern "C" void kernel_launch(void* const* d_in, const int* in_sizes, int n_in,
                              void* d_out, int out_size, void* d_ws, size_t ws_size,
                              hipStream_t stream) {
  const float* x    = (const float*)d_in[0];
  const float* bbox = (const float*)d_in[1];
  const float* W1   = (const float*)d_in[2];
  const float* b1   = (const float*)d_in[3];
  const float* W2   = (const float*)d_in[4];
  const float* b2   = (const float*)d_in[5];
  const float* W3   = (const float*)d_in[6];
  const float* b3   = (const float*)d_in[7];
  float* out = (float*)d_out;

  float* feat_t = (float*)d_ws;  // 8*1024*528 floats = 17.3 MB

  mean_transpose<<<dim3(4, 33, 8), 256, 0, stream>>>(x, feat_t);
  roi_mlp<<<R_, 64, 0, stream>>>(feat_t, bbox, W1, b1, W2, b2, W3, b3, out);
}

// Round 5
// 415.431 us; speedup vs baseline: 1.1129x; 1.1129x over previous
//
#include <hip/hip_runtime.h>
#include <hip/hip_bf16.h>
#include <math.h>

#define N_  8
#define C_  528
#define T_  16
#define H_  32
#define W_  32
#define HW_ 1024
#define R_  1024
#define OUT_ 8
#define SR_ 2
#define SCALE_ (1.0f/16.0f)
#define YMAX_ 10   // max bilinear row-support: box extent <=7 px -> <=10 rows

// ---------------------------------------------------------------------------
// Kernel 1: feat_t[n][p][c] = mean_t x[n][c][t][p], NCHW -> N(HW)C transpose.
// (round-3 version: measured at the HBM floor, keep.)
// ---------------------------------------------------------------------------
__global__ __launch_bounds__(256) void mean_transpose(
    const float* __restrict__ x, float* __restrict__ feat_t) {
  const int p0 = blockIdx.x * 256;   // 4 quarters of HW
  const int c0 = blockIdx.y * 16;    // 33 groups * 16 = 528 exact
  const int n  = blockIdx.z;

  __shared__ float tile[4][64][17];  // 17.4 KB

  const int tid  = threadIdx.x;
  const int lane = tid & 63;
  const int w    = tid >> 6;         // wave id 0..3
  const float inv_t = 1.0f / 16.0f;

  #pragma unroll
  for (int k = 0; k < 4; ++k) {
    const int c_local = w * 4 + k;
    const int c = c0 + c_local;
    const float* src = x + ((size_t)(n * C_ + c) * T_) * HW_ + p0 + lane * 4;
    float4 acc = make_float4(0.f, 0.f, 0.f, 0.f);
    #pragma unroll
    for (int t = 0; t < T_; ++t) {
      const float4 v = *(const float4*)(src + t * HW_);  // wave: 1KB contig
      acc.x += v.x; acc.y += v.y; acc.z += v.z; acc.w += v.w;
    }
    tile[0][lane][c_local] = acc.x * inv_t;  // p = 4*lane+0
    tile[1][lane][c_local] = acc.y * inv_t;
    tile[2][lane][c_local] = acc.z * inv_t;
    tile[3][lane][c_local] = acc.w * inv_t;
  }
  __syncthreads();

  // write phase: 256 p-rows x 16 c = 1024 float4, 4 per thread.
  const int c4 = (tid & 3) * 4;
  #pragma unroll
  for (int k = 0; k < 4; ++k) {
    const int p_out = (tid >> 2) + 64 * k;
    const int i = p_out & 3;
    const int l = p_out >> 2;
    float4 v;
    v.x = tile[i][l][c4 + 0];
    v.y = tile[i][l][c4 + 1];
    v.z = tile[i][l][c4 + 2];
    v.w = tile[i][l][c4 + 3];
    *(float4*)&feat_t[((size_t)n * HW_ + p0 + p_out) * C_ + c0 + c4] = v;
  }
}

// ---------------------------------------------------------------------------
// Kernel 2: per-roi ROI-align + mean + MLP. 1024 blocks x 256 threads.
// Proven 414us structure with barrier surgery: 7 barriers -> 4.
//  - init+PhaseA merged (same-wave DS ordering, no barrier needed)
//  - h1 relu finish folded into layer 2 (each k consumed by one part)
//  - layers 2+3 fused into wave 0, register/shfl only (round-4-verified)
// ---------------------------------------------------------------------------
__global__ __launch_bounds__(256) void roi_mlp(
    const float* __restrict__ feat_t, const float* __restrict__ bbox,
    const float* __restrict__ W1, const float* __restrict__ b1,
    const float* __restrict__ W2, const float* __restrict__ b2,
    const float* __restrict__ W3, const float* __restrict__ b3,
    float* __restrict__ out) {
  const int r = blockIdx.x;
  const int tid = threadIdx.x;

  __shared__ float sAy[32], sAx[32];
  __shared__ __align__(16) float pooledP[YMAX_][C_];  // per-Y partials
  __shared__ __align__(16) float pooled[C_];
  __shared__ float h1p[2][128];
  __shared__ int   sbounds[5];  // ylo,yhi,xlo,xhi,bidx

  // --- Phase A: init + per-axis weights + bounds, all in wave 0 -----------
  // (zero-init and atomicAdd are same-wave DS ops -> ordered, no barrier)
  if (tid < 32) {
    sAy[tid] = 0.f;
    sAx[tid] = 0.f;
    const bool is_y = (tid < 16);
    const int  i    = tid & 15;
    const float s1  = bbox[r * 5 + (is_y ? 2 : 1)] * SCALE_ - 0.5f;
    const float s2  = bbox[r * 5 + (is_y ? 4 : 3)] * SCALE_ - 0.5f;
    const float bin = (s2 - s1) * (1.0f / OUT_);
    const float v   = s1 + ((float)i + 0.5f) * (bin * 0.5f);
    const bool valid = (v >= -1.0f) && (v <= (float)H_);
    int lo = 999, hi = -1;
    if (valid) {
      float vc = fminf(fmaxf(v, 0.0f), (float)(H_ - 1));
      float lo_f = floorf(vc);
      float fr = vc - lo_f;
      lo = (int)lo_f;
      hi = min(lo + 1, H_ - 1);
      float* A = is_y ? sAy : sAx;
      atomicAdd(&A[lo], 1.0f - fr);
      atomicAdd(&A[hi], fr);
    }
    int mn = lo, mx = hi;
    #pragma unroll
    for (int m = 8; m >= 1; m >>= 1) {
      mn = min(mn, __shfl_xor(mn, m, 16));
      mx = max(mx, __shfl_xor(mx, m, 16));
    }
    if (tid == 0)  { sbounds[0] = mn; sbounds[1] = mx;
                     sbounds[4] = (int)bbox[r * 5]; }
    if (tid == 16) { sbounds[2] = mn; sbounds[3] = mx; }
  }
  __syncthreads();                                    // B1

  const int ylo = sbounds[0], yhi = sbounds[1];
  const int xlo = sbounds[2], xhi = sbounds[3];
  const int bidx = sbounds[4];
  const int ny = yhi - ylo + 1;
  const int nx = xhi - xlo + 1;

  // --- Phase B: gather, parallel over (Y-row, channel-quad) tasks ---------
  if (ny > 0 && nx > 0) {
    const float* fb = feat_t + (size_t)bidx * HW_ * C_;
    const int ntask = ny * 132;
    for (int t = tid; t < ntask; t += 256) {
      const int yk = t / 132;          // magic-mul div by const
      const int c4 = t - yk * 132;
      const float wy = sAy[ylo + yk];
      const float* rp = fb + (size_t)((ylo + yk) * W_ + xlo) * C_ + c4 * 4;
      float4 rs = make_float4(0.f, 0.f, 0.f, 0.f);
      for (int xk = 0; xk < nx; ++xk) {
        const float wx = sAx[xlo + xk];
        const float4 v = *(const float4*)(rp + (size_t)xk * C_);
        rs.x += wx * v.x; rs.y += wx * v.y; rs.z += wx * v.z; rs.w += wx * v.w;
      }
      rs.x *= wy; rs.y *= wy; rs.z *= wy; rs.w *= wy;
      *(float4*)&pooledP[yk][c4 * 4] = rs;
    }
  }
  __syncthreads();                                    // B2

  // --- reduce partials over Y (132 float4 lanes) --------------------------
  if (tid < 132) {
    const float inv_cnt = 1.0f / 256.0f;
    float4 a = make_float4(0.f, 0.f, 0.f, 0.f);
    for (int yk = 0; yk < ny; ++yk) {
      const float4 v = *(const float4*)&pooledP[yk][tid * 4];
      a.x += v.x; a.y += v.y; a.z += v.z; a.w += v.w;
    }
    a.x *= inv_cnt; a.y *= inv_cnt; a.z *= inv_cnt; a.w *= inv_cnt;
    *(float4*)&pooled[tid * 4] = a;
  }
  __syncthreads();                                    // B3

  // --- Layer 1 (528 -> 128): 2 half-K partials x 128 outputs --------------
  {
    const int j = tid & 127;
    const int half = tid >> 7;
    const int cb = half * 264;
    float acc = 0.f;
    const float* w = W1 + j;
    #pragma unroll 4
    for (int c = cb; c < cb + 264; c += 4) {
      const float4 p = *(const float4*)&pooled[c];
      acc += p.x * w[(size_t)(c + 0) * 128];
      acc += p.y * w[(size_t)(c + 1) * 128];
      acc += p.z * w[(size_t)(c + 2) * 128];
      acc += p.w * w[(size_t)(c + 3) * 128];
    }
    h1p[half][j] = acc;
  }
  __syncthreads();                                    // B4

  // --- Layers 2+3 fused in wave 0: inline relu finish, shfl reduce --------
  if (tid < 64) {
    const int j  = tid & 31;
    const int kh = tid >> 5;             // K-half 0/1
    float acc = 0.f;
    #pragma unroll 8
    for (int i = 0; i < 64; ++i) {
      const int k = kh * 64 + i;
      const float h1k = fmaxf(h1p[0][k] + h1p[1][k] + b1[k], 0.f);
      acc += h1k * W2[k * 32 + j];
    }
    acc += __shfl_xor(acc, 32);          // combine K-halves
    float t = (acc + b2[j]) * W3[j];
    #pragma unroll
    for (int off = 16; off >= 1; off >>= 1) t += __shfl_xor(t, off, 32);
    if (tid == 0) out[r] = 1.0f / (1.0f + expf(-(t + b3[0])));
  }
}

extern "C" void kernel_launch(void* const* d_in, const int* in_sizes, int n_in,
                              void* d_out, int out_size, void* d_ws, size_t ws_size,
                              hipStream_t stream) {
  const float* x    = (const float*)d_in[0];
  const float* bbox = (const float*)d_in[1];
  const float* W1   = (const float*)d_in[2];
  const float* b1   = (const float*)d_in[3];
  const float* W2   = (const float*)d_in[4];
  const float* b2   = (const float*)d_in[5];
  const float* W3   = (const float*)d_in[6];
  const float* b3   = (const float*)d_in[7];
  float* out = (float*)d_out;

  float* feat_t = (float*)d_ws;  // 8*1024*528 floats = 17.3 MB

  mean_transpose<<<dim3(4, 33, 8), 256, 0, stream>>>(x, feat_t);
  roi_mlp<<<R_, 256, 0, stream>>>(feat_t, bbox, W1, b1, W2, b2, W3, b3, out);
}

// Round 6
// 403.254 us; speedup vs baseline: 1.1465x; 1.0302x over previous
//
#include <hip/hip_runtime.h>
#include <hip/hip_bf16.h>
#include <math.h>

#define N_  8
#define C_  528
#define T_  16
#define H_  32
#define W_  32
#define HW_ 1024
#define R_  1024
#define OUT_ 8
#define SR_ 2
#define SCALE_ (1.0f/16.0f)
#define YMAX_ 10   // max bilinear row-support: box extent <=7 px -> <=10 rows

// ---------------------------------------------------------------------------
// Kernel 1: feat_t[n][p][c] = mean_t x[n][c][t][p], NCHW -> N(HW)C transpose.
// (round-3 version: measured at the HBM floor, keep.)
// ---------------------------------------------------------------------------
__global__ __launch_bounds__(256) void mean_transpose(
    const float* __restrict__ x, float* __restrict__ feat_t) {
  const int p0 = blockIdx.x * 256;   // 4 quarters of HW
  const int c0 = blockIdx.y * 16;    // 33 groups * 16 = 528 exact
  const int n  = blockIdx.z;

  __shared__ float tile[4][64][17];  // 17.4 KB

  const int tid  = threadIdx.x;
  const int lane = tid & 63;
  const int w    = tid >> 6;         // wave id 0..3
  const float inv_t = 1.0f / 16.0f;

  #pragma unroll
  for (int k = 0; k < 4; ++k) {
    const int c_local = w * 4 + k;
    const int c = c0 + c_local;
    const float* src = x + ((size_t)(n * C_ + c) * T_) * HW_ + p0 + lane * 4;
    float4 acc = make_float4(0.f, 0.f, 0.f, 0.f);
    #pragma unroll
    for (int t = 0; t < T_; ++t) {
      const float4 v = *(const float4*)(src + t * HW_);  // wave: 1KB contig
      acc.x += v.x; acc.y += v.y; acc.z += v.z; acc.w += v.w;
    }
    tile[0][lane][c_local] = acc.x * inv_t;  // p = 4*lane+0
    tile[1][lane][c_local] = acc.y * inv_t;
    tile[2][lane][c_local] = acc.z * inv_t;
    tile[3][lane][c_local] = acc.w * inv_t;
  }
  __syncthreads();

  // write phase: 256 p-rows x 16 c = 1024 float4, 4 per thread.
  const int c4 = (tid & 3) * 4;
  #pragma unroll
  for (int k = 0; k < 4; ++k) {
    const int p_out = (tid >> 2) + 64 * k;
    const int i = p_out & 3;
    const int l = p_out >> 2;
    float4 v;
    v.x = tile[i][l][c4 + 0];
    v.y = tile[i][l][c4 + 1];
    v.z = tile[i][l][c4 + 2];
    v.w = tile[i][l][c4 + 3];
    *(float4*)&feat_t[((size_t)n * HW_ + p0 + p_out) * C_ + c0 + c4] = v;
  }
}

// ---------------------------------------------------------------------------
// Kernel 2: per-roi ROI-align + mean + MLP. 1024 blocks x 256 threads.
// Round-5 structure + layer-1 W1 loads vectorized to float4:
//   thread = (j-quad 0..31, K-part 0..7), 66-c slice each.
//   VMEM instrs for W1: 1056 -> 264 wave-instrs per block (4x fewer).
// ---------------------------------------------------------------------------
__global__ __launch_bounds__(256) void roi_mlp(
    const float* __restrict__ feat_t, const float* __restrict__ bbox,
    const float* __restrict__ W1, const float* __restrict__ b1,
    const float* __restrict__ W2, const float* __restrict__ b2,
    const float* __restrict__ W3, const float* __restrict__ b3,
    float* __restrict__ out) {
  const int r = blockIdx.x;
  const int tid = threadIdx.x;

  __shared__ float sAy[32], sAx[32];
  __shared__ __align__(16) float pooledP[YMAX_][C_];  // per-Y partials
  __shared__ __align__(16) float pooled[C_];
  __shared__ __align__(16) float h1p[8][128];         // 8 K-part partials
  __shared__ float h1[128];
  __shared__ int   sbounds[5];  // ylo,yhi,xlo,xhi,bidx

  // --- Phase A: init + per-axis weights + bounds, all in wave 0 -----------
  if (tid < 32) {
    sAy[tid] = 0.f;
    sAx[tid] = 0.f;
    const bool is_y = (tid < 16);
    const int  i    = tid & 15;
    const float s1  = bbox[r * 5 + (is_y ? 2 : 1)] * SCALE_ - 0.5f;
    const float s2  = bbox[r * 5 + (is_y ? 4 : 3)] * SCALE_ - 0.5f;
    const float bin = (s2 - s1) * (1.0f / OUT_);
    const float v   = s1 + ((float)i + 0.5f) * (bin * 0.5f);
    const bool valid = (v >= -1.0f) && (v <= (float)H_);
    int lo = 999, hi = -1;
    if (valid) {
      float vc = fminf(fmaxf(v, 0.0f), (float)(H_ - 1));
      float lo_f = floorf(vc);
      float fr = vc - lo_f;
      lo = (int)lo_f;
      hi = min(lo + 1, H_ - 1);
      float* A = is_y ? sAy : sAx;
      atomicAdd(&A[lo], 1.0f - fr);
      atomicAdd(&A[hi], fr);
    }
    int mn = lo, mx = hi;
    #pragma unroll
    for (int m = 8; m >= 1; m >>= 1) {
      mn = min(mn, __shfl_xor(mn, m, 16));
      mx = max(mx, __shfl_xor(mx, m, 16));
    }
    if (tid == 0)  { sbounds[0] = mn; sbounds[1] = mx;
                     sbounds[4] = (int)bbox[r * 5]; }
    if (tid == 16) { sbounds[2] = mn; sbounds[3] = mx; }
  }
  __syncthreads();                                    // B1

  const int ylo = sbounds[0], yhi = sbounds[1];
  const int xlo = sbounds[2], xhi = sbounds[3];
  const int bidx = sbounds[4];
  const int ny = yhi - ylo + 1;
  const int nx = xhi - xlo + 1;

  // --- Phase B: gather, parallel over (Y-row, channel-quad) tasks ---------
  if (ny > 0 && nx > 0) {
    const float* fb = feat_t + (size_t)bidx * HW_ * C_;
    const int ntask = ny * 132;
    for (int t = tid; t < ntask; t += 256) {
      const int yk = t / 132;          // magic-mul div by const
      const int c4 = t - yk * 132;
      const float wy = sAy[ylo + yk];
      const float* rp = fb + (size_t)((ylo + yk) * W_ + xlo) * C_ + c4 * 4;
      float4 rs = make_float4(0.f, 0.f, 0.f, 0.f);
      for (int xk = 0; xk < nx; ++xk) {
        const float wx = sAx[xlo + xk];
        const float4 v = *(const float4*)(rp + (size_t)xk * C_);
        rs.x += wx * v.x; rs.y += wx * v.y; rs.z += wx * v.z; rs.w += wx * v.w;
      }
      rs.x *= wy; rs.y *= wy; rs.z *= wy; rs.w *= wy;
      *(float4*)&pooledP[yk][c4 * 4] = rs;
    }
  }
  __syncthreads();                                    // B2

  // --- reduce partials over Y (132 float4 lanes) --------------------------
  if (tid < 132) {
    const float inv_cnt = 1.0f / 256.0f;
    float4 a = make_float4(0.f, 0.f, 0.f, 0.f);
    for (int yk = 0; yk < ny; ++yk) {
      const float4 v = *(const float4*)&pooledP[yk][tid * 4];
      a.x += v.x; a.y += v.y; a.z += v.z; a.w += v.w;
    }
    a.x *= inv_cnt; a.y *= inv_cnt; a.z *= inv_cnt; a.w *= inv_cnt;
    *(float4*)&pooled[tid * 4] = a;
  }
  __syncthreads();                                    // B3

  // --- Layer 1 (528 -> 128): float4 W1 loads, 32 j-quads x 8 K-parts ------
  {
    const int jq   = tid & 31;          // j-quad: outputs 4*jq..4*jq+3
    const int part = tid >> 5;          // K-part 0..7
    const int cb   = part * 66;
    float4 acc = make_float4(0.f, 0.f, 0.f, 0.f);
    const float4* w = (const float4*)W1 + jq;   // row stride = 32 float4
    #pragma unroll 6
    for (int c = cb; c < cb + 66; ++c) {
      const float4 wv = w[(size_t)c * 32];
      const float pv = pooled[c];       // LDS broadcast per 32-lane group
      acc.x += pv * wv.x; acc.y += pv * wv.y;
      acc.z += pv * wv.z; acc.w += pv * wv.w;
    }
    *(float4*)&h1p[part][jq * 4] = acc;
  }
  __syncthreads();                                    // B4

  // --- h1 finish: relu(sum of 8 partials + b1) ----------------------------
  if (tid < 128) {
    float a = b1[tid];
    #pragma unroll
    for (int p = 0; p < 8; ++p) a += h1p[p][tid];
    h1[tid] = fmaxf(a, 0.f);
  }
  __syncthreads();                                    // B5

  // --- Layers 2+3 fused in wave 0, shfl reduce ----------------------------
  if (tid < 64) {
    const int j  = tid & 31;
    const int kh = tid >> 5;             // K-half 0/1
    float acc = 0.f;
    #pragma unroll 8
    for (int i = 0; i < 64; ++i) {
      const int k = kh * 64 + i;
      acc += h1[k] * W2[k * 32 + j];
    }
    acc += __shfl_xor(acc, 32);          // combine K-halves
    float t = (acc + b2[j]) * W3[j];
    #pragma unroll
    for (int off = 16; off >= 1; off >>= 1) t += __shfl_xor(t, off, 32);
    if (tid == 0) out[r] = 1.0f / (1.0f + expf(-(t + b3[0])));
  }
}

extern "C" void kernel_launch(void* const* d_in, const int* in_sizes, int n_in,
                              void* d_out, int out_size, void* d_ws, size_t ws_size,
                              hipStream_t stream) {
  const float* x    = (const float*)d_in[0];
  const float* bbox = (const float*)d_in[1];
  const float* W1   = (const float*)d_in[2];
  const float* b1   = (const float*)d_in[3];
  const float* W2   = (const float*)d_in[4];
  const float* b2   = (const float*)d_in[5];
  const float* W3   = (const float*)d_in[6];
  const float* b3   = (const float*)d_in[7];
  float* out = (float*)d_out;

  float* feat_t = (float*)d_ws;  // 8*1024*528 floats = 17.3 MB

  mean_transpose<<<dim3(4, 33, 8), 256, 0, stream>>>(x, feat_t);
  roi_mlp<<<R_, 256, 0, stream>>>(feat_t, bbox, W1, b1, W2, b2, W3, b3, out);
}